// Round 7
// baseline (7663.971 us; speedup 1.0000x reference)
//
#include <hip/hip_runtime.h>
#include <hip/hip_fp16.h>

#define D 128
#define BN 64  // nodes per bucket / per aggB block

// ===========================================================================
// Phase A: partition edges into per-bucket record lists.
// Record: packed = other | (key&63)<<24  (other < 2^17), weighted adds fp32 w.
// ===========================================================================
struct AJob {
    const int* key;    // bucket-side node id per edge
    const int* other;  // gather-side node id per edge
    const float* w;    // nullptr -> 4B records
    int* rec;          // record storage, bucket b at rec[(long)b*cap*(w?2:1)]
    int cbase;         // base into concatenated gcur
    int cap, K, E;
};
struct AJobs5 { AJob j[5]; };

__global__ __launch_bounds__(256) void partA_kernel(AJobs5 J,
                                                    int* __restrict__ gcur) {
    __shared__ int hist[1568];
    __shared__ int klds[4096];
    AJob jb = J.j[blockIdx.y];
    long e0 = (long)blockIdx.x * 4096;
    if (e0 >= jb.E) return;  // uniform per block
    int t = threadIdx.x;
    for (int i = t; i < jb.K; i += 256) hist[i] = 0;
    __syncthreads();
    int nE = (jb.E - e0) < 4096 ? (int)(jb.E - e0) : 4096;
    for (int i = t; i < nE; i += 256) {
        int k = jb.key[e0 + i];
        klds[i] = k;
        atomicAdd(&hist[k >> 6], 1);
    }
    __syncthreads();
    for (int b = t; b < jb.K; b += 256) {
        int c = hist[b];
        if (c) hist[b] = atomicAdd(&gcur[jb.cbase + b], c);  // count -> base
    }
    __syncthreads();
    bool hasw = (jb.w != nullptr);
    for (int i = t; i < nE; i += 256) {
        int k = klds[i];
        int bkt = k >> 6;
        int slot = atomicAdd(&hist[bkt], 1);
        if (slot >= jb.cap) continue;  // ~never (8-sigma cap)
        int packed = jb.other[e0 + i] | ((k & 63) << 24);
        if (hasw)
            ((int2*)jb.rec)[(long)bkt * jb.cap + slot] =
                make_int2(packed, __float_as_int(jb.w[e0 + i]));
        else
            jb.rec[(long)bkt * jb.cap + slot] = packed;
    }
}

// ===========================================================================
// fp32 -> fp16 conversion (x_node table)
// ===========================================================================
__global__ void f2h_kernel(const float2* __restrict__ in, __half2* __restrict__ o,
                           long n2) {
    long i = (long)blockIdx.x * blockDim.x + threadIdx.x;
    if (i < n2) o[i] = __float22half2_rn(in[i]);
}

// ===========================================================================
// Phase B: one block per bucket. 64x128 fp32 accumulator in LDS; waves
// stream records, gather fp16 rows (lane owns cols l and l+64 -> ds_add
// lands 2 lanes/bank = conflict-free), ds_add accumulate, epilogue mean
// (+optional combine with fp32 xb, *0.5) and write fp16 or fp32 row.
// ===========================================================================
template <bool RECW, bool USEW, bool COMBINE, bool OUTH>
__global__ __launch_bounds__(256) void aggB_kernel(
    const __half* __restrict__ vals, const void* __restrict__ rec,
    const int* __restrict__ gcnt, int cap, const float* __restrict__ xb,
    __half* __restrict__ outh, float* __restrict__ outf, int N) {
    __shared__ float acc[BN * D];
    __shared__ int cnt[BN];
    int tid = threadIdx.x;
    int b = blockIdx.x;
    for (int i = tid; i < BN * D / 4; i += 256)
        ((float4*)acc)[i] = make_float4(0.f, 0.f, 0.f, 0.f);
    if (tid < BN) cnt[tid] = 0;
    __syncthreads();

    int m = gcnt[b];
    if (m > cap) m = cap;
    int lane = tid & 63;
    int wv = tid >> 6;
    const int2* recw = (const int2*)rec + (long)b * cap;
    const int* reci = (const int*)rec + (long)b * cap;

    for (int base = wv * 64; base < m; base += 256) {
        int n = m - base;
        if (n > 64) n = 64;
        int packed = 0;
        float wt = 0.f;
        if (lane < n) {
            if (RECW) {
                int2 p = recw[base + lane];
                packed = p.x;
                wt = __int_as_float(p.y);
            } else {
                packed = reci[base + lane];
            }
            atomicAdd(&cnt[(packed >> 24) & 63], 1);
        }
        int j = 0;
        for (; j + 1 < n; j += 2) {
            int p0 = __shfl(packed, j, 64), p1 = __shfl(packed, j + 1, 64);
            int g0 = p0 & 0xFFFFFF, l0 = (p0 >> 24) & 63;
            int g1 = p1 & 0xFFFFFF, l1 = (p1 >> 24) & 63;
            const __half* r0 = vals + (long)g0 * D;
            const __half* r1 = vals + (long)g1 * D;
            float a0 = __half2float(r0[lane]);
            float b0 = __half2float(r0[64 + lane]);
            float a1 = __half2float(r1[lane]);
            float b1 = __half2float(r1[64 + lane]);
            if (USEW) {
                float w0 = __shfl(wt, j, 64), w1 = __shfl(wt, j + 1, 64);
                a0 *= w0; b0 *= w0; a1 *= w1; b1 *= w1;
            }
            atomicAdd(&acc[l0 * D + lane], a0);
            atomicAdd(&acc[l0 * D + 64 + lane], b0);
            atomicAdd(&acc[l1 * D + lane], a1);
            atomicAdd(&acc[l1 * D + 64 + lane], b1);
        }
        for (; j < n; ++j) {
            int p0 = __shfl(packed, j, 64);
            int g0 = p0 & 0xFFFFFF, l0 = (p0 >> 24) & 63;
            const __half* r0 = vals + (long)g0 * D;
            float a0 = __half2float(r0[lane]);
            float b0 = __half2float(r0[64 + lane]);
            if (USEW) {
                float w0 = __shfl(wt, j, 64);
                a0 *= w0; b0 *= w0;
            }
            atomicAdd(&acc[l0 * D + lane], a0);
            atomicAdd(&acc[l0 * D + 64 + lane], b0);
        }
    }
    __syncthreads();

    int r = tid >> 2, q = tid & 3;  // row r, col-quarter q (32 cols)
    int node = b * BN + r;
    if (node >= N) return;
    float inv = 1.0f / fmaxf((float)cnt[r], 1.0f);
#pragma unroll
    for (int i = 0; i < 8; ++i) {
        int c = q * 32 + i * 4;
        float4 s = *(float4*)&acc[r * D + c];
        s.x *= inv; s.y *= inv; s.z *= inv; s.w *= inv;
        if (COMBINE) {
            float4 x = *(const float4*)(xb + (long)node * D + c);
            s.x = (s.x + x.x) * 0.5f;
            s.y = (s.y + x.y) * 0.5f;
            s.z = (s.z + x.z) * 0.5f;
            s.w = (s.w + x.w) * 0.5f;
        }
        if (OUTH) {
            __half2* p = (__half2*)(outh + (long)node * D + c);
            p[0] = __floats2half2_rn(s.x, s.y);
            p[1] = __floats2half2_rn(s.z, s.w);
        } else {
            *(float4*)(outf + (long)node * D + c) = s;
        }
    }
}

// ===========================================================================
// post = relu(pre @ W^T + b), in place on pre. HALF: pre is fp16.
// BM=32, BN=128, BK=64, 256 threads, 2x8 micro-tile.
// ===========================================================================
template <bool HALF>
__global__ __launch_bounds__(256) void linrelu_kernel(
    void* __restrict__ prev, const float* __restrict__ W,
    const float* __restrict__ bias, int N) {
    __half* preh = (__half*)prev;
    float* pref = (float*)prev;
    __shared__ __align__(16) float Wt[64 * D];
    __shared__ __align__(16) float At[64 * 32];
    int tid = threadIdx.x;
    int m0 = blockIdx.x * 32;
    int tn = (tid & 15) * 8;
    int tm = (tid >> 4) * 2;

    float acc[2][8];
#pragma unroll
    for (int i = 0; i < 2; ++i)
#pragma unroll
        for (int j = 0; j < 8; ++j) acc[i][j] = 0.0f;

    for (int kk = 0; kk < 2; ++kk) {
        int kbase = kk * 64;
#pragma unroll
        for (int j = 0; j < 8; ++j) {
            int idx4 = tid + j * 256;
            int n = idx4 & 127;
            int kloc = (idx4 >> 7) * 4;
            float4 v = *(const float4*)(W + (long)n * D + kbase + kloc);
            Wt[(kloc + 0) * D + n] = v.x;
            Wt[(kloc + 1) * D + n] = v.y;
            Wt[(kloc + 2) * D + n] = v.z;
            Wt[(kloc + 3) * D + n] = v.w;
        }
#pragma unroll
        for (int j = 0; j < 2; ++j) {
            int idx4 = tid + j * 256;
            int m = idx4 & 31;
            int kloc = (idx4 >> 5) * 4;
            float4 v = {0.f, 0.f, 0.f, 0.f};
            if (m0 + m < N) {
                if (HALF) {
                    const __half2* p =
                        (const __half2*)(preh + (long)(m0 + m) * D + kbase + kloc);
                    float2 f0 = __half22float2(p[0]);
                    float2 f1 = __half22float2(p[1]);
                    v = make_float4(f0.x, f0.y, f1.x, f1.y);
                } else {
                    v = *(const float4*)(pref + (long)(m0 + m) * D + kbase + kloc);
                }
            }
            At[(kloc + 0) * 32 + m] = v.x;
            At[(kloc + 1) * 32 + m] = v.y;
            At[(kloc + 2) * 32 + m] = v.z;
            At[(kloc + 3) * 32 + m] = v.w;
        }
        __syncthreads();
#pragma unroll
        for (int kloc = 0; kloc < 64; ++kloc) {
            float a0 = At[kloc * 32 + tm];
            float a1 = At[kloc * 32 + tm + 1];
            float4 b0 = *(const float4*)&Wt[kloc * D + tn];
            float4 b1 = *(const float4*)&Wt[kloc * D + tn + 4];
            acc[0][0] += a0 * b0.x; acc[0][1] += a0 * b0.y;
            acc[0][2] += a0 * b0.z; acc[0][3] += a0 * b0.w;
            acc[0][4] += a0 * b1.x; acc[0][5] += a0 * b1.y;
            acc[0][6] += a0 * b1.z; acc[0][7] += a0 * b1.w;
            acc[1][0] += a1 * b0.x; acc[1][1] += a1 * b0.y;
            acc[1][2] += a1 * b0.z; acc[1][3] += a1 * b0.w;
            acc[1][4] += a1 * b1.x; acc[1][5] += a1 * b1.y;
            acc[1][6] += a1 * b1.z; acc[1][7] += a1 * b1.w;
        }
        __syncthreads();
    }
    float4 bv0 = *(const float4*)(bias + tn);
    float4 bv1 = *(const float4*)(bias + tn + 4);
#pragma unroll
    for (int i = 0; i < 2; ++i) {
        int node = m0 + tm + i;
        if (node >= N) continue;
        float o[8];
        o[0] = fmaxf(acc[i][0] + bv0.x, 0.f);
        o[1] = fmaxf(acc[i][1] + bv0.y, 0.f);
        o[2] = fmaxf(acc[i][2] + bv0.z, 0.f);
        o[3] = fmaxf(acc[i][3] + bv0.w, 0.f);
        o[4] = fmaxf(acc[i][4] + bv1.x, 0.f);
        o[5] = fmaxf(acc[i][5] + bv1.y, 0.f);
        o[6] = fmaxf(acc[i][6] + bv1.z, 0.f);
        o[7] = fmaxf(acc[i][7] + bv1.w, 0.f);
        if (HALF) {
            __half2* p = (__half2*)(preh + (long)node * D + tn);
            p[0] = __floats2half2_rn(o[0], o[1]);
            p[1] = __floats2half2_rn(o[2], o[3]);
            p[2] = __floats2half2_rn(o[4], o[5]);
            p[3] = __floats2half2_rn(o[6], o[7]);
        } else {
            *(float4*)(pref + (long)node * D + tn) = make_float4(o[0], o[1], o[2], o[3]);
            *(float4*)(pref + (long)node * D + tn + 4) = make_float4(o[4], o[5], o[6], o[7]);
        }
    }
}

// ===========================================================================
// Attention; one wave per node. p1,p2 fp16; p3 fp32 (aliases out).
// ===========================================================================
__global__ __launch_bounds__(256) void attn_kernel(
    const __half* __restrict__ p1, const __half* __restrict__ p2,
    const float* __restrict__ p3, const float* __restrict__ att,
    float* __restrict__ out, int N) {
    int gw = (int)(((long)blockIdx.x * 256 + threadIdx.x) >> 6);
    int lane = threadIdx.x & 63;
    if (gw >= N) return;
    float2 v1 = __half22float2(((const __half2*)(p1 + (long)gw * D))[lane]);
    float2 v2 = __half22float2(((const __half2*)(p2 + (long)gw * D))[lane]);
    float2 v3 = *(const float2*)(p3 + (long)gw * D + lane * 2);
    float2 a1 = *(const float2*)(att + 0 * D + lane * 2);
    float2 a2 = *(const float2*)(att + 1 * D + lane * 2);
    float2 a3 = *(const float2*)(att + 2 * D + lane * 2);
    float s1 = v1.x * a1.x + v1.y * a1.y;
    float s2 = v2.x * a2.x + v2.y * a2.y;
    float s3 = v3.x * a3.x + v3.y * a3.y;
#pragma unroll
    for (int off = 32; off > 0; off >>= 1) {
        s1 += __shfl_xor(s1, off, 64);
        s2 += __shfl_xor(s2, off, 64);
        s3 += __shfl_xor(s3, off, 64);
    }
    float m = fmaxf(s1, fmaxf(s2, s3));
    float e1 = __expf(s1 - m), e2 = __expf(s2 - m), e3 = __expf(s3 - m);
    float inv = 1.0f / (e1 + e2 + e3);
    float w1 = e1 * inv, w2 = e2 * inv, w3 = e3 * inv;
    float2 o;
    o.x = v1.x * w1 + v2.x * w2 + v3.x * w3;
    o.y = v1.y * w1 + v2.y * w2 + v3.y * w3;
    *(float2*)(out + (long)gw * D + lane * 2) = o;
}

// ===========================================================================
extern "C" void kernel_launch(void* const* d_in, const int* in_sizes, int n_in,
                              void* d_out, int out_size, void* d_ws,
                              size_t ws_size, hipStream_t stream) {
    const float* x_node = (const float*)d_in[0];
    const float* x1 = (const float*)d_in[1];
    const float* x2 = (const float*)d_in[2];
    const int* ei1_src = (const int*)d_in[3];
    const int* ei1_dst = (const int*)d_in[4];
    const int* ei2_src = (const int*)d_in[5];
    const int* ei2_dst = (const int*)d_in[6];
    const int* ei12_src = (const int*)d_in[7];
    const int* ei12_dst = (const int*)d_in[8];
    const float* ew1 = (const float*)d_in[9];
    const float* ew2 = (const float*)d_in[10];
    const float* W1 = (const float*)d_in[11];
    const float* b1 = (const float*)d_in[12];
    const float* W2 = (const float*)d_in[13];
    const float* b2 = (const float*)d_in[14];
    const float* W12 = (const float*)d_in[15];
    const float* b12 = (const float*)d_in[16];
    const float* att = (const float*)d_in[17];
    float* out = (float*)d_out;

    const int N0 = in_sizes[0] / D;
    const int N1 = in_sizes[1] / D;
    const int N2 = in_sizes[2] / D;
    const int E1 = in_sizes[3];
    const int E2 = in_sizes[5];
    const int E12 = in_sizes[7];

    const int K_d1 = (N1 + BN - 1) / BN, K_d2 = (N2 + BN - 1) / BN;
    const int K_d12 = (N2 + BN - 1) / BN;
    const int K_s1 = (N0 + BN - 1) / BN, K_s2 = (N0 + BN - 1) / BN;
    auto capf = [](long E, int K) {
        int mean = (int)((E + K - 1) / K);
        int c = mean + (int)(8.0f * sqrtf((float)mean)) + 16;
        return (c + 15) & ~15;
    };
    const int cap_d1 = capf(E1, K_d1), cap_d2 = capf(E2, K_d2);
    const int cap_d12 = capf(E12, K_d12);
    const int cap_s1 = capf(E1, K_s1), cap_s2 = capf(E2, K_s2);

    float* ws = (float*)d_ws;
    size_t off = 0;
    auto A = [](size_t v) { return (v + 3) & ~(size_t)3; };  // 16B align (words)

    __half* xh = (__half*)(ws + off);     off += A((size_t)N0 * D / 2);
    __half* net1h = (__half*)(ws + off);  off += A((size_t)N1 * D / 2);
    __half* net2h = (__half*)(ws + off);  off += A((size_t)N2 * D / 2);
    __half* net2bh = (__half*)(ws + off); off += A((size_t)N2 * D / 2);
    __half* pre1h = (__half*)(ws + off);  off += A((size_t)N0 * D / 2);
    __half* pre2h = (__half*)(ws + off);  off += A((size_t)N0 * D / 2);
    int* rec_d1 = (int*)(ws + off);  off += A((size_t)K_d1 * cap_d1 * 2);
    int* rec_d2 = (int*)(ws + off);  off += A((size_t)K_d2 * cap_d2 * 2);
    int* rec_d12 = (int*)(ws + off); off += A((size_t)K_d12 * cap_d12);
    int* rec_s1 = (int*)(ws + off);  off += A((size_t)K_s1 * cap_s1);
    int* rec_s2 = (int*)(ws + off);  off += A((size_t)K_s2 * cap_s2 * 2);
    const int KT = K_d1 + K_d2 + K_d12 + K_s1 + K_s2;
    int* gcur = (int*)(ws + off); off += A(KT);
    const int cb_d1 = 0, cb_d2 = K_d1, cb_d12 = K_d1 + K_d2;
    const int cb_s1 = K_d1 + K_d2 + K_d12, cb_s2 = cb_s1 + K_s1;

    hipMemsetAsync((void*)gcur, 0, (size_t)KT * sizeof(int), stream);

    long n2 = (long)N0 * D / 2;
    f2h_kernel<<<(n2 + 255) / 256, 256, 0, stream>>>((const float2*)x_node,
                                                     (__half2*)xh, n2);

    // Phase A: partition all 5 jobs (1 launch)
    AJobs5 J;
    J.j[0] = {ei1_dst, ei1_src, ew1, rec_d1, cb_d1, cap_d1, K_d1, E1};
    J.j[1] = {ei2_dst, ei2_src, ew2, rec_d2, cb_d2, cap_d2, K_d2, E2};
    J.j[2] = {ei12_dst, ei12_src, nullptr, rec_d12, cb_d12, cap_d12, K_d12, E12};
    J.j[3] = {ei1_src, ei1_dst, nullptr, rec_s1, cb_s1, cap_s1, K_s1, E1};
    J.j[4] = {ei2_src, ei2_dst, ew2, rec_s2, cb_s2, cap_s2, K_s2, E2};
    int Emax = E1 > E2 ? E1 : E2;
    if (E12 > Emax) Emax = E12;
    int gax = (Emax + 4095) / 4096;
    partA_kernel<<<dim3(gax, 5), 256, 0, stream>>>(J, gcur);

    // Phase B aggregations (LDS accumulate; no payload re-scans, no fp atomics)
    // net1h = (mean_{d1}(xh[src]*w) + x1)*0.5
    aggB_kernel<true, true, true, true><<<K_d1, 256, 0, stream>>>(
        xh, rec_d1, gcur + cb_d1, cap_d1, x1, net1h, nullptr, N1);
    // net2h = (mean_{d2}(xh[src]*w) + x2)*0.5
    aggB_kernel<true, true, true, true><<<K_d2, 256, 0, stream>>>(
        xh, rec_d2, gcur + cb_d2, cap_d2, x2, net2h, nullptr, N2);
    // net2bh = (mean_{d12}(net1h[src]) + x2)*0.5
    aggB_kernel<false, false, true, true><<<K_d12, 256, 0, stream>>>(
        net1h, rec_d12, gcur + cb_d12, cap_d12, x2, net2bh, nullptr, N2);
    // pre1h = mean_{s1}(net1h[dst])
    aggB_kernel<false, false, false, true><<<K_s1, 256, 0, stream>>>(
        net1h, rec_s1, gcur + cb_s1, cap_s1, nullptr, pre1h, nullptr, N0);
    // pre2h = mean_{s2}(net2h[dst])  (weighted records, weight unused)
    aggB_kernel<true, false, false, true><<<K_s2, 256, 0, stream>>>(
        net2h, rec_s2, gcur + cb_s2, cap_s2, nullptr, pre2h, nullptr, N0);
    // pre3 (fp32, into d_out) = mean_{s2}(net2bh[dst]*w)
    aggB_kernel<true, true, false, false><<<K_s2, 256, 0, stream>>>(
        net2bh, rec_s2, gcur + cb_s2, cap_s2, nullptr, nullptr, out, N0);

    // linear + relu (in place)
    const int gb = (N0 + 31) / 32;
    linrelu_kernel<true><<<gb, 256, 0, stream>>>(pre1h, W1, b1, N0);
    linrelu_kernel<true><<<gb, 256, 0, stream>>>(pre2h, W2, b2, N0);
    linrelu_kernel<false><<<gb, 256, 0, stream>>>(out, W12, b12, N0);

    // attention combine (p3 aliases out; read-before-write per element)
    attn_kernel<<<(N0 + 3) / 4, 256, 0, stream>>>(pre1h, pre2h, out, att, out, N0);
}